// Round 1
// 239.602 us; speedup vs baseline: 1.1051x; 1.1051x over previous
//
#include <hip/hip_runtime.h>
#include <hip/hip_bf16.h>

#define B_   4
#define M_   8192
#define N_   32768
#define H_   128
#define EPS_ 1e-5f
#define TBL  1048576   // 4 * 64^3 dense hash table
#define GUARD 8192     // negative-offset guard for window probes

typedef short short8 __attribute__((ext_vector_type(8)));   // 8 bf16 (4 VGPRs)
typedef float f32x4  __attribute__((ext_vector_type(4)));   // 4 fp32 acc

// ---------------------------------------------------------------- prep
__global__ __launch_bounds__(256) void prep_kernel(const int* __restrict__ coords,
                                                   int* __restrict__ table,
                                                   int* __restrict__ packed,
                                                   int* __restrict__ keyb,
                                                   float* __restrict__ gsum,
                                                   unsigned int* __restrict__ hbz) {
    int n = blockIdx.x * 256 + threadIdx.x;
    int b = coords[4*n+0], x = coords[4*n+1], y = coords[4*n+2], z = coords[4*n+3];
    packed[n] = (x << 10) | (y << 5) | z;
    int key = ((b*64 + x+1)*64 + y+1)*64 + (z+1);
    keyb[n] = key;
    table[key] = n;
    if (blockIdx.x == 0) gsum[threadIdx.x] = 0.f;            // 256 floats (BN2 stats acc)
    if (blockIdx.x == 1 && threadIdx.x < 64) hbz[threadIdx.x] = 0u;  // 256B zero row
}

// ---------------------------------------------------------------- w3 -> bf16 MFMA B-fragment layout
// w3f[t*8+j], t = (o<<11)|(ks<<9)|(ct<<6)|lane :
//   value = bf16(w3[o][c][n]), c = ks*32 + (lane>>4)*8 + j, n = ct*16 + (lane&15)
__global__ __launch_bounds__(256) void w3pack_kernel(const float* __restrict__ w3,
                                                     ushort* __restrict__ w3f) {
    int t = blockIdx.x * 256 + threadIdx.x;   // 27*2048 = 55296 threads exactly
    int lane = t & 63;
    int ct   = (t >> 6) & 7;
    int ks   = (t >> 9) & 3;
    int o    = t >> 11;
    int quad = lane >> 4, l15 = lane & 15;
    int n = ct*16 + l15;
    const float* src = w3 + o*16384;
    ushort out8[8];
#pragma unroll
    for (int j = 0; j < 8; ++j) {
        int c = ks*32 + quad*8 + j;
        float v = src[c*128 + n];
        __hip_bfloat16 bv = __float2bfloat16(v);
        ushort u; __builtin_memcpy(&u, &bv, 2);
        out8[j] = u;
    }
    *(uint4*)&w3f[t*8] = *(uint4*)out8;
}

// ---------------------------------------------------------------- kNN via radius-2 window
__global__ __launch_bounds__(256) void knn_window_kernel(const int* __restrict__ table,
                                                         const int* __restrict__ keyb,
                                                         int* __restrict__ nbr,
                                                         int* __restrict__ flagcnt,
                                                         int* __restrict__ flaglist) {
    __shared__ int okey_sh[125], d2_sh[125];
    __shared__ int tops[256 * 8];
    int tid = threadIdx.x;
    if (tid < 125) {
        int dx = tid / 25 - 2, rr = tid % 25, dy = rr / 5 - 2, dz = rr % 5 - 2;
        okey_sh[tid] = dx * 4096 + dy * 64 + dz;
        d2_sh[tid]   = dx*dx + dy*dy + dz*dz;
    }
    __syncthreads();

    int q   = blockIdx.x * 64 + (tid >> 2);
    int sub = tid & 3;
    int kb  = keyb[q];

    int top[8];
#pragma unroll
    for (int k = 0; k < 8; ++k) top[k] = 0x7FFFFFFF;

    int base = sub * 32;
    int cnt  = (sub == 3) ? 29 : 32;
    for (int i = 0; i < cnt; ++i) {
        int idx = base + i;
        int j = table[kb + okey_sh[idx]];
        if (j >= 0) {
            int key = (d2_sh[idx] << 13) | (j & 8191);
            if (key < top[7]) {
#pragma unroll
                for (int k = 7; k >= 1; --k)
                    top[k] = (key < top[k]) ? max(key, top[k-1]) : top[k];
                top[0] = min(key, top[0]);
            }
        }
    }
#pragma unroll
    for (int k = 0; k < 8; ++k) tops[tid*8 + k] = top[k];
    __syncthreads();

    if (sub == 0) {
        const int* L = &tops[tid*8];
        int ia0 = 0, ia1 = 0, ia2 = 0, ia3 = 0;
        int res[8];
#pragma unroll
        for (int k = 0; k < 8; ++k) {
            int v0 = L[ia0], v1 = L[8 + ia1], v2 = L[16 + ia2], v3 = L[24 + ia3];
            int m01 = min(v0, v1), m23 = min(v2, v3);
            int m = min(m01, m23);
            res[k] = m;
            if (m == v0) ++ia0; else if (m == v1) ++ia1;
            else if (m == v2) ++ia2; else ++ia3;
        }
        int bb = q & ~(M_-1);
        if ((res[7] >> 13) <= 8) {
#pragma unroll
            for (int k = 0; k < 8; ++k) nbr[q*8 + k] = bb + (res[k] & 8191);
        } else {
            int pos = atomicAdd(flagcnt, 1);
            flaglist[pos] = q;
        }
    }
}

// ---------------------------------------------------------------- brute-force cleanup
__global__ __launch_bounds__(256) void knn_bf_kernel(const int* __restrict__ packed,
                                                     const int* __restrict__ flagcnt,
                                                     const int* __restrict__ flaglist,
                                                     int* __restrict__ nbr) {
    __shared__ int tops[256 * 8];
    int tid = threadIdx.x;
    int cnt = *flagcnt;
    for (int f = blockIdx.x; f < cnt; f += gridDim.x) {
        int n = flaglist[f];
        int bb = n & ~(M_-1);
        int p = packed[n];
        int qx = (p >> 10) & 31, qy = (p >> 5) & 31, qz = p & 31;
        int top[8];
#pragma unroll
        for (int k = 0; k < 8; ++k) top[k] = 0x7FFFFFFF;
        for (int j = tid; j < M_; j += 256) {
            int c = packed[bb + j];
            int dx = qx - ((c >> 10) & 31);
            int dy = qy - ((c >> 5) & 31);
            int dz = qz - (c & 31);
            int d2 = dx*dx + dy*dy + dz*dz;
            int key = (d2 << 13) | j;
            if (key < top[7]) {
#pragma unroll
                for (int k = 7; k >= 1; --k)
                    top[k] = (key < top[k]) ? max(key, top[k-1]) : top[k];
                top[0] = min(key, top[0]);
            }
        }
#pragma unroll
        for (int k = 0; k < 8; ++k) tops[tid*8 + k] = top[k];
        __syncthreads();
        for (int stride = 128; stride >= 1; stride >>= 1) {
            if (tid < stride) {
                int* A  = &tops[tid*8];
                int* Bp = &tops[(tid+stride)*8];
                int r[8]; int ia = 0, ib = 0;
#pragma unroll
                for (int k = 0; k < 8; ++k) {
                    int a = A[ia], b2 = Bp[ib];
                    if (a <= b2) { r[k] = a; ++ia; } else { r[k] = b2; ++ib; }
                }
#pragma unroll
                for (int k = 0; k < 8; ++k) A[k] = r[k];
            }
            __syncthreads();
        }
        if (tid == 0) {
#pragma unroll
            for (int k = 0; k < 8; ++k) nbr[n*8 + k] = bb + (tops[k] & 8191);
        }
        __syncthreads();
    }
}

// ---------------------------------------------------------------- 1x1 conv (combined @ w1)
__global__ __launch_bounds__(256) void h1_kernel(const float* __restrict__ feats,
                                                 const int* __restrict__ nbr,
                                                 const float* __restrict__ w1,
                                                 float* __restrict__ hpre) {
    __shared__ float comb[16][72];
    int tid = threadIdx.x;
    int rowbase = blockIdx.x * 16;
    if (tid < 144) {
        int r = tid / 9, s = tid % 9;
        int grow = rowbase + r;
        int idx = (s == 0) ? grow : nbr[grow*8 + (s-1)];
        const float4* f = (const float4*)(feats + idx * 8);
        float4 a = f[0], b = f[1];
        float* dp = &comb[r][s*8];
        dp[0]=a.x; dp[1]=a.y; dp[2]=a.z; dp[3]=a.w;
        dp[4]=b.x; dp[5]=b.y; dp[6]=b.z; dp[7]=b.w;
    }
    __syncthreads();
    int c = tid & 127, rh = tid >> 7;
    float acc[8];
#pragma unroll
    for (int i = 0; i < 8; ++i) acc[i] = 0.f;
    for (int s = 0; s < 72; ++s) {
        float w = w1[s*128 + c];
#pragma unroll
        for (int i = 0; i < 8; ++i)
            acc[i] += comb[rh*8 + i][s] * w;
    }
#pragma unroll
    for (int i = 0; i < 8; ++i)
        hpre[(rowbase + rh*8 + i)*128 + c] = acc[i];
}

// ---------------------------------------------------------------- BN stats (h1 path)
__global__ __launch_bounds__(256) void reduce_kernel(const float* __restrict__ src,
                                                     float* __restrict__ part) {
    __shared__ float ssum[256], ssq[256];
    int tid = threadIdx.x;
    int c = tid & 127, halfr = tid >> 7;
    int rowbase = blockIdx.x * 128 + halfr * 64;
    float s = 0.f, q = 0.f;
    for (int i = 0; i < 64; ++i) {
        float v = src[(rowbase + i)*128 + c];
        s += v; q += v*v;
    }
    ssum[tid] = s; ssq[tid] = q;
    __syncthreads();
    if (tid < 128) {
        part[blockIdx.x*256 + tid]       = ssum[tid] + ssum[tid+128];
        part[blockIdx.x*256 + 128 + tid] = ssq[tid]  + ssq[tid+128];
    }
}

__global__ __launch_bounds__(128) void stats_kernel(const float* __restrict__ part,
                                                    const float* __restrict__ g,
                                                    const float* __restrict__ bias,
                                                    float* __restrict__ scale,
                                                    float* __restrict__ shift) {
    int c = threadIdx.x;
    float s = 0.f, q = 0.f;
    for (int b = 0; b < 256; ++b) {
        s += part[b*256 + c];
        q += part[b*256 + 128 + c];
    }
    float mu  = s / (float)N_;
    float var = q / (float)N_ - mu*mu;
    float inv = rsqrtf(var + EPS_);
    float sc  = inv * g[c];
    scale[c] = sc;
    shift[c] = bias[c] - mu * sc;
}

// BN2 stats from direct sums (conv3 epilogue accumulates gsum)
__global__ __launch_bounds__(128) void stats2_kernel(const float* __restrict__ gsum,
                                                     const float* __restrict__ g,
                                                     const float* __restrict__ bias,
                                                     float* __restrict__ scale,
                                                     float* __restrict__ shift) {
    int c = threadIdx.x;
    float s = gsum[c], q = gsum[128 + c];
    float mu  = s / (float)N_;
    float var = q / (float)N_ - mu*mu;
    float inv = rsqrtf(var + EPS_);
    float sc  = inv * g[c];
    scale[c] = sc;
    shift[c] = bias[c] - mu * sc;
}

// BN+ReLU -> bf16 output (for conv3 A operand)
__global__ __launch_bounds__(256) void bnrelu_bf16_kernel(const float* __restrict__ x,
                                                          const float* __restrict__ scale,
                                                          const float* __restrict__ shift,
                                                          ushort* __restrict__ y) {
    int i = blockIdx.x * 256 + threadIdx.x;
    float4 v = ((const float4*)x)[i];
    int c = (i * 4) & 127;
    v.x = fmaxf(0.f, v.x*scale[c]   + shift[c]);
    v.y = fmaxf(0.f, v.y*scale[c+1] + shift[c+1]);
    v.z = fmaxf(0.f, v.z*scale[c+2] + shift[c+2]);
    v.w = fmaxf(0.f, v.w*scale[c+3] + shift[c+3]);
    ushort o[4];
#pragma unroll
    for (int k = 0; k < 4; ++k) {
        float f = (&v.x)[k];
        __hip_bfloat16 bv = __float2bfloat16(f);
        __builtin_memcpy(&o[k], &bv, 2);
    }
    ((ushort4*)y)[i] = make_ushort4(o[0], o[1], o[2], o[3]);
}

// ---------------------------------------------------------------- 3^3 sparse conv: pipelined bf16 MFMA gather-GEMM
// block: 64 rows x 128 cols, 4 waves (each 32 rows x 64 cols = 2x4 tiles of 16x16)
// A: double-buffered LDS via global_load_lds (linear dest, XOR-chunk-swizzled source+read)
// B: per-wave register fragments straight from L2-resident w3f (no LDS staging)
// one __syncthreads per offset, AFTER compute -> next-tile stage overlaps MFMAs
__global__ __launch_bounds__(256) void conv3_mfma_kernel(const ushort* __restrict__ hb,
                                                         const ushort* __restrict__ w3f,
                                                         const int* __restrict__ table,
                                                         const int* __restrict__ keyb,
                                                         float* __restrict__ h2,
                                                         float* __restrict__ gsum) {
    __shared__ ushort As[2][64 * 128];   // 2 x 16 KB, [row][chunk^(row&15)]
    __shared__ int jsh[27 * 64];         // all gather rows, precomputed
    __shared__ int kbsh[64];
    int tid = threadIdx.x;
    int lane = tid & 63, wid = tid >> 6;
    int quad = lane >> 4, l15 = lane & 15;
    int bid = blockIdx.x;
    int swz = (bid & 7) * 64 + (bid >> 3);   // XCD-chunked, bijective (512 % 8 == 0)
    int rowbase = swz * 64;
    int rb = (wid >> 1) * 2;        // row-tile base (0 or 2)
    int cb = (wid & 1) * 4;         // col-tile base (0 or 4)

    if (tid < 64) kbsh[tid] = keyb[rowbase + tid];
    __syncthreads();
    // all 27x64 table lookups up front (invalid stays -1 -> zero row at hb - 128)
    for (int t = tid; t < 27*64; t += 256) {
        int o = t >> 6, r = t & 63;
        int dx = o/9 - 1, dy = (o/3)%3 - 1, dz = o%3 - 1;
        jsh[t] = table[kbsh[r] + dx*4096 + dy*64 + dz];
    }
    __syncthreads();

    // stage A for o=0
#pragma unroll
    for (int i = 0; i < 4; ++i) {
        int flat = i*256 + tid;
        int r = flat >> 4, cp = flat & 15;
        int j = jsh[r];
        const ushort* src = hb + j*128 + ((cp ^ (r & 15)) << 3);
        __builtin_amdgcn_global_load_lds(
            (const __attribute__((address_space(1))) unsigned int*)src,
            (__attribute__((address_space(3))) unsigned int*)&As[0][flat << 3],
            16, 0, 0);
    }
    __syncthreads();   // drains vmcnt(0): A(0) resident

    f32x4 acc[2][4];
#pragma unroll
    for (int i = 0; i < 2; ++i)
#pragma unroll
        for (int c = 0; c < 4; ++c)
            acc[i][c] = (f32x4){0.f, 0.f, 0.f, 0.f};

    int cur = 0;
#pragma unroll 1
    for (int o = 0; o < 27; ++o) {
        // B fragments for this offset -> registers (coalesced 16B/lane, L1/L2-hot)
        short8 bfr[4][4];
        const ushort* wb = w3f + (o << 14) + (cb << 9) + (lane << 3);
#pragma unroll
        for (int ks = 0; ks < 4; ++ks)
#pragma unroll
            for (int c = 0; c < 4; ++c)
                bfr[ks][c] = *(const short8*)(wb + (ks << 12) + (c << 9));
        // stage A(o+1) into the other buffer; completes during MFMAs below
        if (o < 26) {
#pragma unroll
            for (int i = 0; i < 4; ++i) {
                int flat = i*256 + tid;
                int r = flat >> 4, cp = flat & 15;
                int j = jsh[(o+1)*64 + r];
                const ushort* src = hb + j*128 + ((cp ^ (r & 15)) << 3);
                __builtin_amdgcn_global_load_lds(
                    (const __attribute__((address_space(1))) unsigned int*)src,
                    (__attribute__((address_space(3))) unsigned int*)&As[cur ^ 1][flat << 3],
                    16, 0, 0);
            }
        }
        // compute on As[cur]: swizzled chunk read -> conflict-free ds_read_b128
#pragma unroll
        for (int ks = 0; ks < 4; ++ks) {
            short8 af[2];
#pragma unroll
            for (int i = 0; i < 2; ++i) {
                int lr = (rb + i)*16 + l15;
                int chunk = (ks*4 + quad) ^ l15;
                af[i] = *(const short8*)&As[cur][lr*128 + chunk*8];
            }
#pragma unroll
            for (int i = 0; i < 2; ++i)
#pragma unroll
                for (int c = 0; c < 4; ++c)
                    acc[i][c] = __builtin_amdgcn_mfma_f32_16x16x32_bf16(af[i], bfr[ks][c], acc[i][c], 0, 0, 0);
        }
        __syncthreads();   // drains vmcnt(0): A(o+1) landed; everyone done reading As[cur]
        cur ^= 1;
    }

    // epilogue: store h2 + per-column BN2 partial sums
    float s[4], q[4];
#pragma unroll
    for (int c = 0; c < 4; ++c) { s[c] = 0.f; q[c] = 0.f; }
#pragma unroll
    for (int i = 0; i < 2; ++i)
#pragma unroll
        for (int c = 0; c < 4; ++c)
#pragma unroll
            for (int r = 0; r < 4; ++r) {
                int row = rowbase + (rb + i)*16 + quad*4 + r;
                int col = (cb + c)*16 + l15;
                float v = acc[i][c][r];
                h2[row*128 + col] = v;
                s[c] += v; q[c] += v*v;
            }
    float* red = (float*)&As[0][0];   // 256 floats: sums[128] | sqs[128]
    red[tid] = 0.f;
    __syncthreads();
#pragma unroll
    for (int c = 0; c < 4; ++c) {
        int col = (cb + c)*16 + l15;
        atomicAdd(&red[col], s[c]);
        atomicAdd(&red[128 + col], q[c]);
    }
    __syncthreads();
    atomicAdd(&gsum[tid], red[tid]);
}

// ---------------------------------------------------------------- final 1x1 conv, fused BN2+ReLU
__global__ __launch_bounds__(256) void out_kernel(const float* __restrict__ h2,
                                                  const float* __restrict__ wout,
                                                  const float* __restrict__ scale,
                                                  const float* __restrict__ shift,
                                                  float* __restrict__ out) {
    __shared__ float sc[128], sh[128];
    int tid = threadIdx.x;
    if (tid < 128) { sc[tid] = scale[tid]; sh[tid] = shift[tid]; }
    __syncthreads();
    int r = tid >> 4, d = tid & 15;
    int row = blockIdx.x * 16 + r;
    float acc = 0.f;
    for (int c = 0; c < 128; ++c) {
        float hv = fmaxf(0.f, fmaf(h2[row*128 + c], sc[c], sh[c]));
        acc = fmaf(hv, wout[c*16 + d], acc);
    }
    out[row*16 + d] = acc;
}

// ---------------------------------------------------------------- launch
extern "C" void kernel_launch(void* const* d_in, const int* in_sizes, int n_in,
                              void* d_out, int out_size, void* d_ws, size_t ws_size,
                              hipStream_t stream) {
    const int*   coords = (const int*)d_in[0];
    const float* feats  = (const float*)d_in[1];
    const float* w1     = (const float*)d_in[2];
    const float* g1     = (const float*)d_in[3];
    const float* b1     = (const float*)d_in[4];
    const float* w3     = (const float*)d_in[5];
    const float* g2     = (const float*)d_in[6];
    const float* b2     = (const float*)d_in[7];
    const float* wout   = (const float*)d_in[8];
    float* out = (float*)d_out;

    char* ws = (char*)d_ws;
    int*    table_base = (int*)(ws);                              // 4.03 MB
    int*    table   = table_base + GUARD;
    int*    packed  = (int*)(ws + (4352u<<10));                   // 128 KB
    int*    keyb    = (int*)(ws + (4608u<<10));                   // 128 KB
    int*    nbr     = (int*)(ws + (4864u<<10));                   // 1 MB
    int*    flagcnt = (int*)(ws + (5888u<<10));                   // 4 B
    int*    flaglist= (int*)(ws + (5892u<<10));                   // 128 KB
    float*  part    = (float*)(ws + (6144u<<10));                 // 256 KB (BN1 partials)
    float*  scale1  = (float*)(ws + (6400u<<10));
    float*  shift1  = scale1 + 128;
    float*  scale2  = shift1 + 128;
    float*  shift2  = scale2 + 128;
    float*  gsum    = (float*)(ws + (6416u<<10));                 // 1 KB (BN2 direct sums)
    ushort* w3f     = (ushort*)(ws + (6656u<<10));                // 0.88 MB (ends 7520K)
    ushort* hb      = (ushort*)(ws + (7680u<<10));                // 8 MB; hb-128 = 256B zero row
    float*  h       = (float*)(ws + (15872u<<10));                // 16 MB
    float*  h2      = h;   // aliased: h is dead once hb is written, conv3 reads only hb

    hipMemsetAsync(table_base, 0xFF, (TBL + GUARD) * sizeof(int), stream);
    hipMemsetAsync(flagcnt, 0, sizeof(int), stream);
    prep_kernel      <<<N_/256, 256, 0, stream>>>(coords, table, packed, keyb,
                                                  gsum, (unsigned int*)(hb - 128));
    w3pack_kernel    <<<216, 256, 0, stream>>>(w3, w3f);
    knn_window_kernel<<<N_/64, 256, 0, stream>>>(table, keyb, nbr, flagcnt, flaglist);
    knn_bf_kernel    <<<256, 256, 0, stream>>>(packed, flagcnt, flaglist, nbr);
    h1_kernel        <<<N_/16, 256, 0, stream>>>(feats, nbr, w1, h);
    reduce_kernel    <<<N_/128, 256, 0, stream>>>(h, part);
    stats_kernel     <<<1, 128, 0, stream>>>(part, g1, b1, scale1, shift1);
    bnrelu_bf16_kernel<<<(N_*H_/4)/256, 256, 0, stream>>>(h, scale1, shift1, hb);
    conv3_mfma_kernel<<<N_/64, 256, 0, stream>>>(hb, w3f, table, keyb, h2, gsum);
    stats2_kernel    <<<1, 128, 0, stream>>>(gsum, g2, b2, scale2, shift2);
    out_kernel       <<<N_/16, 256, 0, stream>>>(h2, wout, scale2, shift2, out);
}

// Round 2
// 235.232 us; speedup vs baseline: 1.1256x; 1.0186x over previous
//
#include <hip/hip_runtime.h>
#include <hip/hip_bf16.h>

#define B_   4
#define M_   8192
#define N_   32768
#define H_   128
#define EPS_ 1e-5f
#define TBL  1048576   // 4 * 64^3 dense hash table
#define GUARD 8192     // negative-offset guard for window probes

typedef short short8 __attribute__((ext_vector_type(8)));   // 8 bf16 (4 VGPRs)
typedef float f32x4  __attribute__((ext_vector_type(4)));   // 4 fp32 acc

// ---------------------------------------------------------------- prep
__global__ __launch_bounds__(256) void prep_kernel(const int* __restrict__ coords,
                                                   int* __restrict__ table,
                                                   int* __restrict__ packed,
                                                   int* __restrict__ keyb,
                                                   float* __restrict__ gsum,
                                                   unsigned int* __restrict__ hbz) {
    int n = blockIdx.x * 256 + threadIdx.x;
    int b = coords[4*n+0], x = coords[4*n+1], y = coords[4*n+2], z = coords[4*n+3];
    packed[n] = (x << 10) | (y << 5) | z;
    int key = ((b*64 + x+1)*64 + y+1)*64 + (z+1);
    keyb[n] = key;
    table[key] = n;
    if (blockIdx.x == 0) gsum[threadIdx.x] = 0.f;            // 256 floats (BN2 stats acc)
    if (blockIdx.x == 1 && threadIdx.x < 64) hbz[threadIdx.x] = 0u;  // 256B zero row
}

// ---------------------------------------------------------------- w3 -> bf16 MFMA B-fragment layout
// w3f[t*8+j], t = (o<<11)|(ks<<9)|(ct<<6)|lane :
//   value = bf16(w3[o][c][n]), c = ks*32 + (lane>>4)*8 + j, n = ct*16 + (lane&15)
__global__ __launch_bounds__(256) void w3pack_kernel(const float* __restrict__ w3,
                                                     ushort* __restrict__ w3f) {
    int t = blockIdx.x * 256 + threadIdx.x;   // 27*2048 = 55296 threads exactly
    int lane = t & 63;
    int ct   = (t >> 6) & 7;
    int ks   = (t >> 9) & 3;
    int o    = t >> 11;
    int quad = lane >> 4, l15 = lane & 15;
    int n = ct*16 + l15;
    const float* src = w3 + o*16384;
    ushort out8[8];
#pragma unroll
    for (int j = 0; j < 8; ++j) {
        int c = ks*32 + quad*8 + j;
        float v = src[c*128 + n];
        __hip_bfloat16 bv = __float2bfloat16(v);
        ushort u; __builtin_memcpy(&u, &bv, 2);
        out8[j] = u;
    }
    *(uint4*)&w3f[t*8] = *(uint4*)out8;
}

// ---------------------------------------------------------------- kNN via radius-2 window
__global__ __launch_bounds__(256) void knn_window_kernel(const int* __restrict__ table,
                                                         const int* __restrict__ keyb,
                                                         int* __restrict__ nbr,
                                                         int* __restrict__ flagcnt,
                                                         int* __restrict__ flaglist) {
    __shared__ int okey_sh[125], d2_sh[125];
    __shared__ int tops[256 * 8];
    int tid = threadIdx.x;
    if (tid < 125) {
        int dx = tid / 25 - 2, rr = tid % 25, dy = rr / 5 - 2, dz = rr % 5 - 2;
        okey_sh[tid] = dx * 4096 + dy * 64 + dz;
        d2_sh[tid]   = dx*dx + dy*dy + dz*dz;
    }
    __syncthreads();

    int q   = blockIdx.x * 64 + (tid >> 2);
    int sub = tid & 3;
    int kb  = keyb[q];

    int top[8];
#pragma unroll
    for (int k = 0; k < 8; ++k) top[k] = 0x7FFFFFFF;

    int base = sub * 32;
    int cnt  = (sub == 3) ? 29 : 32;
    for (int i = 0; i < cnt; ++i) {
        int idx = base + i;
        int j = table[kb + okey_sh[idx]];
        if (j >= 0) {
            int key = (d2_sh[idx] << 13) | (j & 8191);
            if (key < top[7]) {
#pragma unroll
                for (int k = 7; k >= 1; --k)
                    top[k] = (key < top[k]) ? max(key, top[k-1]) : top[k];
                top[0] = min(key, top[0]);
            }
        }
    }
#pragma unroll
    for (int k = 0; k < 8; ++k) tops[tid*8 + k] = top[k];
    __syncthreads();

    if (sub == 0) {
        const int* L = &tops[tid*8];
        int ia0 = 0, ia1 = 0, ia2 = 0, ia3 = 0;
        int res[8];
#pragma unroll
        for (int k = 0; k < 8; ++k) {
            int v0 = L[ia0], v1 = L[8 + ia1], v2 = L[16 + ia2], v3 = L[24 + ia3];
            int m01 = min(v0, v1), m23 = min(v2, v3);
            int m = min(m01, m23);
            res[k] = m;
            if (m == v0) ++ia0; else if (m == v1) ++ia1;
            else if (m == v2) ++ia2; else ++ia3;
        }
        int bb = q & ~(M_-1);
        if ((res[7] >> 13) <= 8) {
#pragma unroll
            for (int k = 0; k < 8; ++k) nbr[q*8 + k] = bb + (res[k] & 8191);
        } else {
            int pos = atomicAdd(flagcnt, 1);
            flaglist[pos] = q;
        }
    }
}

// ---------------------------------------------------------------- brute-force cleanup
__global__ __launch_bounds__(256) void knn_bf_kernel(const int* __restrict__ packed,
                                                     const int* __restrict__ flagcnt,
                                                     const int* __restrict__ flaglist,
                                                     int* __restrict__ nbr) {
    __shared__ int tops[256 * 8];
    int tid = threadIdx.x;
    int cnt = *flagcnt;
    for (int f = blockIdx.x; f < cnt; f += gridDim.x) {
        int n = flaglist[f];
        int bb = n & ~(M_-1);
        int p = packed[n];
        int qx = (p >> 10) & 31, qy = (p >> 5) & 31, qz = p & 31;
        int top[8];
#pragma unroll
        for (int k = 0; k < 8; ++k) top[k] = 0x7FFFFFFF;
        for (int j = tid; j < M_; j += 256) {
            int c = packed[bb + j];
            int dx = qx - ((c >> 10) & 31);
            int dy = qy - ((c >> 5) & 31);
            int dz = qz - (c & 31);
            int d2 = dx*dx + dy*dy + dz*dz;
            int key = (d2 << 13) | j;
            if (key < top[7]) {
#pragma unroll
                for (int k = 7; k >= 1; --k)
                    top[k] = (key < top[k]) ? max(key, top[k-1]) : top[k];
                top[0] = min(key, top[0]);
            }
        }
#pragma unroll
        for (int k = 0; k < 8; ++k) tops[tid*8 + k] = top[k];
        __syncthreads();
        for (int stride = 128; stride >= 1; stride >>= 1) {
            if (tid < stride) {
                int* A  = &tops[tid*8];
                int* Bp = &tops[(tid+stride)*8];
                int r[8]; int ia = 0, ib = 0;
#pragma unroll
                for (int k = 0; k < 8; ++k) {
                    int a = A[ia], b2 = Bp[ib];
                    if (a <= b2) { r[k] = a; ++ia; } else { r[k] = b2; ++ib; }
                }
#pragma unroll
                for (int k = 0; k < 8; ++k) A[k] = r[k];
            }
            __syncthreads();
        }
        if (tid == 0) {
#pragma unroll
            for (int k = 0; k < 8; ++k) nbr[n*8 + k] = bb + (tops[k] & 8191);
        }
        __syncthreads();
    }
}

// ---------------------------------------------------------------- 1x1 conv (combined @ w1)
__global__ __launch_bounds__(256) void h1_kernel(const float* __restrict__ feats,
                                                 const int* __restrict__ nbr,
                                                 const float* __restrict__ w1,
                                                 float* __restrict__ hpre) {
    __shared__ float comb[16][72];
    int tid = threadIdx.x;
    int rowbase = blockIdx.x * 16;
    if (tid < 144) {
        int r = tid / 9, s = tid % 9;
        int grow = rowbase + r;
        int idx = (s == 0) ? grow : nbr[grow*8 + (s-1)];
        const float4* f = (const float4*)(feats + idx * 8);
        float4 a = f[0], b = f[1];
        float* dp = &comb[r][s*8];
        dp[0]=a.x; dp[1]=a.y; dp[2]=a.z; dp[3]=a.w;
        dp[4]=b.x; dp[5]=b.y; dp[6]=b.z; dp[7]=b.w;
    }
    __syncthreads();
    int c = tid & 127, rh = tid >> 7;
    float acc[8];
#pragma unroll
    for (int i = 0; i < 8; ++i) acc[i] = 0.f;
    for (int s = 0; s < 72; ++s) {
        float w = w1[s*128 + c];
#pragma unroll
        for (int i = 0; i < 8; ++i)
            acc[i] += comb[rh*8 + i][s] * w;
    }
#pragma unroll
    for (int i = 0; i < 8; ++i)
        hpre[(rowbase + rh*8 + i)*128 + c] = acc[i];
}

// ---------------------------------------------------------------- BN stats (h1 path)
__global__ __launch_bounds__(256) void reduce_kernel(const float* __restrict__ src,
                                                     float* __restrict__ part) {
    __shared__ float ssum[256], ssq[256];
    int tid = threadIdx.x;
    int c = tid & 127, halfr = tid >> 7;
    int rowbase = blockIdx.x * 128 + halfr * 64;
    float s = 0.f, q = 0.f;
    for (int i = 0; i < 64; ++i) {
        float v = src[(rowbase + i)*128 + c];
        s += v; q += v*v;
    }
    ssum[tid] = s; ssq[tid] = q;
    __syncthreads();
    if (tid < 128) {
        part[blockIdx.x*256 + tid]       = ssum[tid] + ssum[tid+128];
        part[blockIdx.x*256 + 128 + tid] = ssq[tid]  + ssq[tid+128];
    }
}

__global__ __launch_bounds__(128) void stats_kernel(const float* __restrict__ part,
                                                    const float* __restrict__ g,
                                                    const float* __restrict__ bias,
                                                    float* __restrict__ scale,
                                                    float* __restrict__ shift) {
    int c = threadIdx.x;
    float s = 0.f, q = 0.f;
    for (int b = 0; b < 256; ++b) {
        s += part[b*256 + c];
        q += part[b*256 + 128 + c];
    }
    float mu  = s / (float)N_;
    float var = q / (float)N_ - mu*mu;
    float inv = rsqrtf(var + EPS_);
    float sc  = inv * g[c];
    scale[c] = sc;
    shift[c] = bias[c] - mu * sc;
}

// BN2 stats from direct sums (conv3 epilogue accumulates gsum)
__global__ __launch_bounds__(128) void stats2_kernel(const float* __restrict__ gsum,
                                                     const float* __restrict__ g,
                                                     const float* __restrict__ bias,
                                                     float* __restrict__ scale,
                                                     float* __restrict__ shift) {
    int c = threadIdx.x;
    float s = gsum[c], q = gsum[128 + c];
    float mu  = s / (float)N_;
    float var = q / (float)N_ - mu*mu;
    float inv = rsqrtf(var + EPS_);
    float sc  = inv * g[c];
    scale[c] = sc;
    shift[c] = bias[c] - mu * sc;
}

// BN+ReLU -> bf16 output (for conv3 A operand)
__global__ __launch_bounds__(256) void bnrelu_bf16_kernel(const float* __restrict__ x,
                                                          const float* __restrict__ scale,
                                                          const float* __restrict__ shift,
                                                          ushort* __restrict__ y) {
    int i = blockIdx.x * 256 + threadIdx.x;
    float4 v = ((const float4*)x)[i];
    int c = (i * 4) & 127;
    v.x = fmaxf(0.f, v.x*scale[c]   + shift[c]);
    v.y = fmaxf(0.f, v.y*scale[c+1] + shift[c+1]);
    v.z = fmaxf(0.f, v.z*scale[c+2] + shift[c+2]);
    v.w = fmaxf(0.f, v.w*scale[c+3] + shift[c+3]);
    ushort o[4];
#pragma unroll
    for (int k = 0; k < 4; ++k) {
        float f = (&v.x)[k];
        __hip_bfloat16 bv = __float2bfloat16(f);
        __builtin_memcpy(&o[k], &bv, 2);
    }
    ((ushort4*)y)[i] = make_ushort4(o[0], o[1], o[2], o[3]);
}

// ---------------------------------------------------------------- 3^3 sparse conv: pipelined bf16 MFMA gather-GEMM
// block: 64 rows x 128 cols, 4 waves (each 32 rows x 64 cols = 2x4 tiles of 16x16)
// A: double-buffered LDS via global_load_lds (linear dest, XOR-chunk-swizzled source+read)
// B: double-buffered REGISTER prefetch (bcur/bnxt, named -> stays in VGPRs, no scratch)
//    -> the MFMA phase touches only registers + conflict-free LDS; the single
//       per-iter barrier drain covers both A-stage and B-prefetch latency.
__global__ __launch_bounds__(256) void conv3_mfma_kernel(const ushort* __restrict__ hb,
                                                         const ushort* __restrict__ w3f,
                                                         const int* __restrict__ table,
                                                         const int* __restrict__ keyb,
                                                         float* __restrict__ h2,
                                                         float* __restrict__ gsum) {
    __shared__ ushort As[2][64 * 128];   // 2 x 16 KB, [row][chunk^(row&15)]
    __shared__ int jsh[27 * 64];         // all gather rows, precomputed
    __shared__ int kbsh[64];
    int tid = threadIdx.x;
    int lane = tid & 63, wid = tid >> 6;
    int quad = lane >> 4, l15 = lane & 15;
    int bid = blockIdx.x;
    int swz = (bid & 7) * 64 + (bid >> 3);   // XCD-chunked, bijective (512 % 8 == 0)
    int rowbase = swz * 64;
    int rb = (wid >> 1) * 2;        // row-tile base (0 or 2)
    int cb = (wid & 1) * 4;         // col-tile base (0 or 4)

    if (tid < 64) kbsh[tid] = keyb[rowbase + tid];
    __syncthreads();
    // all 27x64 table lookups up front (invalid stays -1 -> zero row at hb - 128)
    for (int t = tid; t < 27*64; t += 256) {
        int o = t >> 6, r = t & 63;
        int dx = o/9 - 1, dy = (o/3)%3 - 1, dz = o%3 - 1;
        jsh[t] = table[kbsh[r] + dx*4096 + dy*64 + dz];
    }
    __syncthreads();

    // stage A for o=0
#pragma unroll
    for (int i = 0; i < 4; ++i) {
        int flat = i*256 + tid;
        int r = flat >> 4, cp = flat & 15;
        int j = jsh[r];
        const ushort* src = hb + j*128 + ((cp ^ (r & 15)) << 3);
        __builtin_amdgcn_global_load_lds(
            (const __attribute__((address_space(1))) unsigned int*)src,
            (__attribute__((address_space(3))) unsigned int*)&As[0][flat << 3],
            16, 0, 0);
    }
    // preload B fragments for o=0 while A(0) is in flight
    short8 bcur[4][4];
    {
        const ushort* wb = w3f + (cb << 9) + (lane << 3);
#pragma unroll
        for (int ks = 0; ks < 4; ++ks)
#pragma unroll
            for (int c = 0; c < 4; ++c)
                bcur[ks][c] = *(const short8*)(wb + (ks << 12) + (c << 9));
    }
    __syncthreads();   // drains vmcnt(0): A(0) resident, bcur loaded

    f32x4 acc[2][4];
#pragma unroll
    for (int i = 0; i < 2; ++i)
#pragma unroll
        for (int c = 0; c < 4; ++c)
            acc[i][c] = (f32x4){0.f, 0.f, 0.f, 0.f};

    int cur = 0;
#pragma unroll 2
    for (int o = 0; o < 27; ++o) {
        // stage A(o+1) into the other buffer; completes during MFMAs below
        if (o < 26) {
#pragma unroll
            for (int i = 0; i < 4; ++i) {
                int flat = i*256 + tid;
                int r = flat >> 4, cp = flat & 15;
                int j = jsh[(o+1)*64 + r];
                const ushort* src = hb + j*128 + ((cp ^ (r & 15)) << 3);
                __builtin_amdgcn_global_load_lds(
                    (const __attribute__((address_space(1))) unsigned int*)src,
                    (__attribute__((address_space(3))) unsigned int*)&As[cur ^ 1][flat << 3],
                    16, 0, 0);
            }
        }
        // prefetch B(o+1) into named registers; lands by next-iter barrier drain
        short8 bnxt[4][4];
        if (o < 26) {
            const ushort* wb = w3f + ((o + 1) << 14) + (cb << 9) + (lane << 3);
#pragma unroll
            for (int ks = 0; ks < 4; ++ks)
#pragma unroll
                for (int c = 0; c < 4; ++c)
                    bnxt[ks][c] = *(const short8*)(wb + (ks << 12) + (c << 9));
        }
        // compute on As[cur] x bcur: registers + conflict-free ds_read_b128 only
#pragma unroll
        for (int ks = 0; ks < 4; ++ks) {
            short8 af[2];
#pragma unroll
            for (int i = 0; i < 2; ++i) {
                int lr = (rb + i)*16 + l15;
                int chunk = (ks*4 + quad) ^ l15;
                af[i] = *(const short8*)&As[cur][lr*128 + chunk*8];
            }
#pragma unroll
            for (int i = 0; i < 2; ++i)
#pragma unroll
                for (int c = 0; c < 4; ++c)
                    acc[i][c] = __builtin_amdgcn_mfma_f32_16x16x32_bf16(af[i], bcur[ks][c], acc[i][c], 0, 0, 0);
        }
        __syncthreads();   // drains vmcnt(0): A(o+1) + bnxt landed; As[cur] free
        if (o < 26) {
#pragma unroll
            for (int ks = 0; ks < 4; ++ks)
#pragma unroll
                for (int c = 0; c < 4; ++c)
                    bcur[ks][c] = bnxt[ks][c];
        }
        cur ^= 1;
    }

    // epilogue: store h2 + per-column BN2 partial sums
    float s[4], q[4];
#pragma unroll
    for (int c = 0; c < 4; ++c) { s[c] = 0.f; q[c] = 0.f; }
#pragma unroll
    for (int i = 0; i < 2; ++i)
#pragma unroll
        for (int c = 0; c < 4; ++c)
#pragma unroll
            for (int r = 0; r < 4; ++r) {
                int row = rowbase + (rb + i)*16 + quad*4 + r;
                int col = (cb + c)*16 + l15;
                float v = acc[i][c][r];
                h2[row*128 + col] = v;
                s[c] += v; q[c] += v*v;
            }
    float* red = (float*)&As[0][0];   // 256 floats: sums[128] | sqs[128]
    red[tid] = 0.f;
    __syncthreads();
#pragma unroll
    for (int c = 0; c < 4; ++c) {
        int col = (cb + c)*16 + l15;
        atomicAdd(&red[col], s[c]);
        atomicAdd(&red[128 + col], q[c]);
    }
    __syncthreads();
    atomicAdd(&gsum[tid], red[tid]);
}

// ---------------------------------------------------------------- final 1x1 conv, fused BN2+ReLU
__global__ __launch_bounds__(256) void out_kernel(const float* __restrict__ h2,
                                                  const float* __restrict__ wout,
                                                  const float* __restrict__ scale,
                                                  const float* __restrict__ shift,
                                                  float* __restrict__ out) {
    __shared__ float sc[128], sh[128];
    int tid = threadIdx.x;
    if (tid < 128) { sc[tid] = scale[tid]; sh[tid] = shift[tid]; }
    __syncthreads();
    int r = tid >> 4, d = tid & 15;
    int row = blockIdx.x * 16 + r;
    float acc = 0.f;
    for (int c = 0; c < 128; ++c) {
        float hv = fmaxf(0.f, fmaf(h2[row*128 + c], sc[c], sh[c]));
        acc = fmaf(hv, wout[c*16 + d], acc);
    }
    out[row*16 + d] = acc;
}

// ---------------------------------------------------------------- launch
extern "C" void kernel_launch(void* const* d_in, const int* in_sizes, int n_in,
                              void* d_out, int out_size, void* d_ws, size_t ws_size,
                              hipStream_t stream) {
    const int*   coords = (const int*)d_in[0];
    const float* feats  = (const float*)d_in[1];
    const float* w1     = (const float*)d_in[2];
    const float* g1     = (const float*)d_in[3];
    const float* b1     = (const float*)d_in[4];
    const float* w3     = (const float*)d_in[5];
    const float* g2     = (const float*)d_in[6];
    const float* b2     = (const float*)d_in[7];
    const float* wout   = (const float*)d_in[8];
    float* out = (float*)d_out;

    char* ws = (char*)d_ws;
    int*    table_base = (int*)(ws);                              // 4.03 MB
    int*    table   = table_base + GUARD;
    int*    packed  = (int*)(ws + (4352u<<10));                   // 128 KB
    int*    keyb    = (int*)(ws + (4608u<<10));                   // 128 KB
    int*    nbr     = (int*)(ws + (4864u<<10));                   // 1 MB
    int*    flagcnt = (int*)(ws + (5888u<<10));                   // 4 B
    int*    flaglist= (int*)(ws + (5892u<<10));                   // 128 KB
    float*  part    = (float*)(ws + (6144u<<10));                 // 256 KB (BN1 partials)
    float*  scale1  = (float*)(ws + (6400u<<10));
    float*  shift1  = scale1 + 128;
    float*  scale2  = shift1 + 128;
    float*  shift2  = scale2 + 128;
    float*  gsum    = (float*)(ws + (6416u<<10));                 // 1 KB (BN2 direct sums)
    ushort* w3f     = (ushort*)(ws + (6656u<<10));                // 0.88 MB (ends 7520K)
    ushort* hb      = (ushort*)(ws + (7680u<<10));                // 8 MB; hb-128 = 256B zero row
    float*  h       = (float*)(ws + (15872u<<10));                // 16 MB
    float*  h2      = h;   // aliased: h is dead once hb is written, conv3 reads only hb

    hipMemsetAsync(table_base, 0xFF, (TBL + GUARD) * sizeof(int), stream);
    hipMemsetAsync(flagcnt, 0, sizeof(int), stream);
    prep_kernel      <<<N_/256, 256, 0, stream>>>(coords, table, packed, keyb,
                                                  gsum, (unsigned int*)(hb - 128));
    w3pack_kernel    <<<216, 256, 0, stream>>>(w3, w3f);
    knn_window_kernel<<<N_/64, 256, 0, stream>>>(table, keyb, nbr, flagcnt, flaglist);
    knn_bf_kernel    <<<256, 256, 0, stream>>>(packed, flagcnt, flaglist, nbr);
    h1_kernel        <<<N_/16, 256, 0, stream>>>(feats, nbr, w1, h);
    reduce_kernel    <<<N_/128, 256, 0, stream>>>(h, part);
    stats_kernel     <<<1, 128, 0, stream>>>(part, g1, b1, scale1, shift1);
    bnrelu_bf16_kernel<<<(N_*H_/4)/256, 256, 0, stream>>>(h, scale1, shift1, hb);
    conv3_mfma_kernel<<<N_/64, 256, 0, stream>>>(hb, w3f, table, keyb, h2, gsum);
    stats2_kernel    <<<1, 128, 0, stream>>>(gsum, g2, b2, scale2, shift2);
    out_kernel       <<<N_/16, 256, 0, stream>>>(h2, wout, scale2, shift2, out);
}

// Round 3
// 228.398 us; speedup vs baseline: 1.1593x; 1.0299x over previous
//
#include <hip/hip_runtime.h>
#include <hip/hip_bf16.h>

#define B_   4
#define M_   8192
#define N_   32768
#define H_   128
#define EPS_ 1e-5f
#define TBL  1048576   // 4 * 64^3 dense hash table
#define GUARD 8192     // negative-offset guard for window probes

typedef short short8 __attribute__((ext_vector_type(8)));   // 8 bf16 (4 VGPRs)
typedef float f32x4  __attribute__((ext_vector_type(4)));   // 4 fp32 acc

// ---------------------------------------------------------------- prep
__global__ __launch_bounds__(256) void prep_kernel(const int* __restrict__ coords,
                                                   int* __restrict__ table,
                                                   int* __restrict__ packed,
                                                   int* __restrict__ keyb,
                                                   float* __restrict__ gsum,
                                                   unsigned int* __restrict__ hbz) {
    int n = blockIdx.x * 256 + threadIdx.x;
    int b = coords[4*n+0], x = coords[4*n+1], y = coords[4*n+2], z = coords[4*n+3];
    packed[n] = (x << 10) | (y << 5) | z;
    int key = ((b*64 + x+1)*64 + y+1)*64 + (z+1);
    keyb[n] = key;
    table[key] = n;
    if (blockIdx.x == 0) gsum[threadIdx.x] = 0.f;            // 256 floats (BN2 stats acc)
    if (blockIdx.x == 1 && threadIdx.x < 64) hbz[threadIdx.x] = 0u;  // 256B zero row
}

// ---------------------------------------------------------------- w3 -> bf16 MFMA B-fragment layout
// w3f[t*8+j], t = (o<<11)|(ks<<9)|(ct<<6)|lane :
//   value = bf16(w3[o][c][n]), c = ks*32 + (lane>>4)*8 + j, n = ct*16 + (lane&15)
__global__ __launch_bounds__(256) void w3pack_kernel(const float* __restrict__ w3,
                                                     ushort* __restrict__ w3f) {
    int t = blockIdx.x * 256 + threadIdx.x;   // 27*2048 = 55296 threads exactly
    int lane = t & 63;
    int ct   = (t >> 6) & 7;
    int ks   = (t >> 9) & 3;
    int o    = t >> 11;
    int quad = lane >> 4, l15 = lane & 15;
    int n = ct*16 + l15;
    const float* src = w3 + o*16384;
    ushort out8[8];
#pragma unroll
    for (int j = 0; j < 8; ++j) {
        int c = ks*32 + quad*8 + j;
        float v = src[c*128 + n];
        __hip_bfloat16 bv = __float2bfloat16(v);
        ushort u; __builtin_memcpy(&u, &bv, 2);
        out8[j] = u;
    }
    *(uint4*)&w3f[t*8] = *(uint4*)out8;
}

// ---------------------------------------------------------------- kNN via radius-2 window
__global__ __launch_bounds__(256) void knn_window_kernel(const int* __restrict__ table,
                                                         const int* __restrict__ keyb,
                                                         int* __restrict__ nbr,
                                                         int* __restrict__ flagcnt,
                                                         int* __restrict__ flaglist) {
    __shared__ int okey_sh[125], d2_sh[125];
    __shared__ int tops[256 * 8];
    int tid = threadIdx.x;
    if (tid < 125) {
        int dx = tid / 25 - 2, rr = tid % 25, dy = rr / 5 - 2, dz = rr % 5 - 2;
        okey_sh[tid] = dx * 4096 + dy * 64 + dz;
        d2_sh[tid]   = dx*dx + dy*dy + dz*dz;
    }
    __syncthreads();

    int q   = blockIdx.x * 64 + (tid >> 2);
    int sub = tid & 3;
    int kb  = keyb[q];

    int top[8];
#pragma unroll
    for (int k = 0; k < 8; ++k) top[k] = 0x7FFFFFFF;

    int base = sub * 32;
    int cnt  = (sub == 3) ? 29 : 32;
    for (int i = 0; i < cnt; ++i) {
        int idx = base + i;
        int j = table[kb + okey_sh[idx]];
        if (j >= 0) {
            int key = (d2_sh[idx] << 13) | (j & 8191);
            if (key < top[7]) {
#pragma unroll
                for (int k = 7; k >= 1; --k)
                    top[k] = (key < top[k]) ? max(key, top[k-1]) : top[k];
                top[0] = min(key, top[0]);
            }
        }
    }
#pragma unroll
    for (int k = 0; k < 8; ++k) tops[tid*8 + k] = top[k];
    __syncthreads();

    if (sub == 0) {
        const int* L = &tops[tid*8];
        int ia0 = 0, ia1 = 0, ia2 = 0, ia3 = 0;
        int res[8];
#pragma unroll
        for (int k = 0; k < 8; ++k) {
            int v0 = L[ia0], v1 = L[8 + ia1], v2 = L[16 + ia2], v3 = L[24 + ia3];
            int m01 = min(v0, v1), m23 = min(v2, v3);
            int m = min(m01, m23);
            res[k] = m;
            if (m == v0) ++ia0; else if (m == v1) ++ia1;
            else if (m == v2) ++ia2; else ++ia3;
        }
        int bb = q & ~(M_-1);
        if ((res[7] >> 13) <= 8) {
#pragma unroll
            for (int k = 0; k < 8; ++k) nbr[q*8 + k] = bb + (res[k] & 8191);
        } else {
            int pos = atomicAdd(flagcnt, 1);
            flaglist[pos] = q;
        }
    }
}

// ---------------------------------------------------------------- brute-force cleanup
__global__ __launch_bounds__(256) void knn_bf_kernel(const int* __restrict__ packed,
                                                     const int* __restrict__ flagcnt,
                                                     const int* __restrict__ flaglist,
                                                     int* __restrict__ nbr) {
    __shared__ int tops[256 * 8];
    int tid = threadIdx.x;
    int cnt = *flagcnt;
    for (int f = blockIdx.x; f < cnt; f += gridDim.x) {
        int n = flaglist[f];
        int bb = n & ~(M_-1);
        int p = packed[n];
        int qx = (p >> 10) & 31, qy = (p >> 5) & 31, qz = p & 31;
        int top[8];
#pragma unroll
        for (int k = 0; k < 8; ++k) top[k] = 0x7FFFFFFF;
        for (int j = tid; j < M_; j += 256) {
            int c = packed[bb + j];
            int dx = qx - ((c >> 10) & 31);
            int dy = qy - ((c >> 5) & 31);
            int dz = qz - (c & 31);
            int d2 = dx*dx + dy*dy + dz*dz;
            int key = (d2 << 13) | j;
            if (key < top[7]) {
#pragma unroll
                for (int k = 7; k >= 1; --k)
                    top[k] = (key < top[k]) ? max(key, top[k-1]) : top[k];
                top[0] = min(key, top[0]);
            }
        }
#pragma unroll
        for (int k = 0; k < 8; ++k) tops[tid*8 + k] = top[k];
        __syncthreads();
        for (int stride = 128; stride >= 1; stride >>= 1) {
            if (tid < stride) {
                int* A  = &tops[tid*8];
                int* Bp = &tops[(tid+stride)*8];
                int r[8]; int ia = 0, ib = 0;
#pragma unroll
                for (int k = 0; k < 8; ++k) {
                    int a = A[ia], b2 = Bp[ib];
                    if (a <= b2) { r[k] = a; ++ia; } else { r[k] = b2; ++ib; }
                }
#pragma unroll
                for (int k = 0; k < 8; ++k) A[k] = r[k];
            }
            __syncthreads();
        }
        if (tid == 0) {
#pragma unroll
            for (int k = 0; k < 8; ++k) nbr[n*8 + k] = bb + (tops[k] & 8191);
        }
        __syncthreads();
    }
}

// ---------------------------------------------------------------- 1x1 conv (combined @ w1)
__global__ __launch_bounds__(256) void h1_kernel(const float* __restrict__ feats,
                                                 const int* __restrict__ nbr,
                                                 const float* __restrict__ w1,
                                                 float* __restrict__ hpre) {
    __shared__ float comb[16][72];
    int tid = threadIdx.x;
    int rowbase = blockIdx.x * 16;
    if (tid < 144) {
        int r = tid / 9, s = tid % 9;
        int grow = rowbase + r;
        int idx = (s == 0) ? grow : nbr[grow*8 + (s-1)];
        const float4* f = (const float4*)(feats + idx * 8);
        float4 a = f[0], b = f[1];
        float* dp = &comb[r][s*8];
        dp[0]=a.x; dp[1]=a.y; dp[2]=a.z; dp[3]=a.w;
        dp[4]=b.x; dp[5]=b.y; dp[6]=b.z; dp[7]=b.w;
    }
    __syncthreads();
    int c = tid & 127, rh = tid >> 7;
    float acc[8];
#pragma unroll
    for (int i = 0; i < 8; ++i) acc[i] = 0.f;
    for (int s = 0; s < 72; ++s) {
        float w = w1[s*128 + c];
#pragma unroll
        for (int i = 0; i < 8; ++i)
            acc[i] += comb[rh*8 + i][s] * w;
    }
#pragma unroll
    for (int i = 0; i < 8; ++i)
        hpre[(rowbase + rh*8 + i)*128 + c] = acc[i];
}

// ---------------------------------------------------------------- BN stats (h1 path)
__global__ __launch_bounds__(256) void reduce_kernel(const float* __restrict__ src,
                                                     float* __restrict__ part) {
    __shared__ float ssum[256], ssq[256];
    int tid = threadIdx.x;
    int c = tid & 127, halfr = tid >> 7;
    int rowbase = blockIdx.x * 128 + halfr * 64;
    float s = 0.f, q = 0.f;
    for (int i = 0; i < 64; ++i) {
        float v = src[(rowbase + i)*128 + c];
        s += v; q += v*v;
    }
    ssum[tid] = s; ssq[tid] = q;
    __syncthreads();
    if (tid < 128) {
        part[blockIdx.x*256 + tid]       = ssum[tid] + ssum[tid+128];
        part[blockIdx.x*256 + 128 + tid] = ssq[tid]  + ssq[tid+128];
    }
}

__global__ __launch_bounds__(128) void stats_kernel(const float* __restrict__ part,
                                                    const float* __restrict__ g,
                                                    const float* __restrict__ bias,
                                                    float* __restrict__ scale,
                                                    float* __restrict__ shift) {
    int c = threadIdx.x;
    float s = 0.f, q = 0.f;
    for (int b = 0; b < 256; ++b) {
        s += part[b*256 + c];
        q += part[b*256 + 128 + c];
    }
    float mu  = s / (float)N_;
    float var = q / (float)N_ - mu*mu;
    float inv = rsqrtf(var + EPS_);
    float sc  = inv * g[c];
    scale[c] = sc;
    shift[c] = bias[c] - mu * sc;
}

// BN2 stats from direct sums (conv3 epilogue accumulates gsum)
__global__ __launch_bounds__(128) void stats2_kernel(const float* __restrict__ gsum,
                                                     const float* __restrict__ g,
                                                     const float* __restrict__ bias,
                                                     float* __restrict__ scale,
                                                     float* __restrict__ shift) {
    int c = threadIdx.x;
    float s = gsum[c], q = gsum[128 + c];
    float mu  = s / (float)N_;
    float var = q / (float)N_ - mu*mu;
    float inv = rsqrtf(var + EPS_);
    float sc  = inv * g[c];
    scale[c] = sc;
    shift[c] = bias[c] - mu * sc;
}

// BN+ReLU -> bf16 output (for conv3 A operand)
__global__ __launch_bounds__(256) void bnrelu_bf16_kernel(const float* __restrict__ x,
                                                          const float* __restrict__ scale,
                                                          const float* __restrict__ shift,
                                                          ushort* __restrict__ y) {
    int i = blockIdx.x * 256 + threadIdx.x;
    float4 v = ((const float4*)x)[i];
    int c = (i * 4) & 127;
    v.x = fmaxf(0.f, v.x*scale[c]   + shift[c]);
    v.y = fmaxf(0.f, v.y*scale[c+1] + shift[c+1]);
    v.z = fmaxf(0.f, v.z*scale[c+2] + shift[c+2]);
    v.w = fmaxf(0.f, v.w*scale[c+3] + shift[c+3]);
    ushort o[4];
#pragma unroll
    for (int k = 0; k < 4; ++k) {
        float f = (&v.x)[k];
        __hip_bfloat16 bv = __float2bfloat16(f);
        __builtin_memcpy(&o[k], &bv, 2);
    }
    ((ushort4*)y)[i] = make_ushort4(o[0], o[1], o[2], o[3]);
}

// ---------------------------------------------------------------- 3^3 sparse conv: pipelined bf16 MFMA gather-GEMM
// block: 128 rows x 128 cols, 8 waves (each 32 rows x 64 cols = 2x4 tiles of 16x16)
// Rationale (R2): conv3 was L1/vector-memory-BW bound. B traffic scales with
// block count -> fewer, bigger blocks (grid 256, 1/CU) + B staged ONCE per block
// into LDS (removes 2x intra-block register duplication). Per-CU-iter global
// bytes: 160 KB -> 64 KB. A and B double-buffered via global_load_lds, single
// barrier per offset. 145 KB dynamic LDS (gfx950 allows 160 KB/workgroup).
#define CONV3_LDS 145408
__global__ __launch_bounds__(512) void conv3_mfma_kernel(const ushort* __restrict__ hb,
                                                         const ushort* __restrict__ w3f,
                                                         const int* __restrict__ table,
                                                         const int* __restrict__ keyb,
                                                         float* __restrict__ h2,
                                                         float* __restrict__ gsum) {
    extern __shared__ char smem_raw[];
    ushort* Asb = (ushort*)smem_raw;                 // 2 x 32768 B  [buf][row 0..127][chunk^(row&15)]
    ushort* Bsb = (ushort*)(smem_raw + 65536);       // 2 x 32768 B  fragment-major copy of w3f[o]
    int*    jsh = (int*)(smem_raw + 131072);         // 27*128*4 = 13824 B
    int*    kbsh= (int*)(smem_raw + 144896);         // 512 B

    int tid = threadIdx.x;
    int lane = tid & 63, wid = tid >> 6;
    int quad = lane >> 4, l15 = lane & 15;
    int bid = blockIdx.x;
    int swz = (bid & 7) * 32 + (bid >> 3);   // XCD-chunked, bijective (256 % 8 == 0)
    int rowbase = swz * 128;
    int wr = wid >> 1;              // row group 0..3 (32 rows each)
    int cb = (wid & 1) * 4;         // col-tile base (0 or 4)

    if (tid < 128) kbsh[tid] = keyb[rowbase + tid];
    __syncthreads();
    // all 27x128 table lookups up front (invalid stays -1 -> zero row at hb - 128)
    for (int t = tid; t < 27*128; t += 512) {
        int o = t >> 7, r = t & 127;
        int dx = o/9 - 1, dy = (o/3)%3 - 1, dz = o%3 - 1;
        jsh[t] = table[kbsh[r] + dx*4096 + dy*64 + dz];
    }
    __syncthreads();

    // stage A(0) + B(0)
#pragma unroll
    for (int i = 0; i < 4; ++i) {
        int flat = i*512 + tid;             // 2048 chunks of 16B each
        int r = flat >> 4, cp = flat & 15;
        int j = jsh[r];
        const ushort* asrc = hb + j*128 + ((cp ^ (r & 15)) << 3);
        __builtin_amdgcn_global_load_lds(
            (const __attribute__((address_space(1))) unsigned int*)asrc,
            (__attribute__((address_space(3))) unsigned int*)&Asb[flat << 3],
            16, 0, 0);
        __builtin_amdgcn_global_load_lds(
            (const __attribute__((address_space(1))) unsigned int*)(w3f + (flat << 3)),
            (__attribute__((address_space(3))) unsigned int*)&Bsb[flat << 3],
            16, 0, 0);
    }
    __syncthreads();   // drains vmcnt(0): A(0), B(0) resident

    f32x4 acc[2][4];
#pragma unroll
    for (int i = 0; i < 2; ++i)
#pragma unroll
        for (int c = 0; c < 4; ++c)
            acc[i][c] = (f32x4){0.f, 0.f, 0.f, 0.f};

    int cur = 0;
#pragma unroll 1
    for (int o = 0; o < 27; ++o) {
        // stage A(o+1), B(o+1) into the other buffers; complete during MFMAs below
        if (o < 26) {
            int obase = (o + 1) << 7;
            const ushort* wsrc = w3f + ((o + 1) << 14);
            int dst = (cur ^ 1) * 16384;
#pragma unroll
            for (int i = 0; i < 4; ++i) {
                int flat = i*512 + tid;
                int r = flat >> 4, cp = flat & 15;
                int j = jsh[obase + r];
                const ushort* asrc = hb + j*128 + ((cp ^ (r & 15)) << 3);
                __builtin_amdgcn_global_load_lds(
                    (const __attribute__((address_space(1))) unsigned int*)asrc,
                    (__attribute__((address_space(3))) unsigned int*)&Asb[dst + (flat << 3)],
                    16, 0, 0);
                __builtin_amdgcn_global_load_lds(
                    (const __attribute__((address_space(1))) unsigned int*)(wsrc + (flat << 3)),
                    (__attribute__((address_space(3))) unsigned int*)&Bsb[dst + (flat << 3)],
                    16, 0, 0);
            }
        }
        // compute on buffers[cur]: conflict-free ds_read_b128 only
        const ushort* Ac = Asb + cur*16384;
        const ushort* Bc = Bsb + cur*16384;
#pragma unroll
        for (int ks = 0; ks < 4; ++ks) {
            short8 af[2], bfr[4];
#pragma unroll
            for (int i = 0; i < 2; ++i) {
                int lr = wr*32 + i*16 + l15;
                int chunk = (ks*4 + quad) ^ l15;
                af[i] = *(const short8*)&Ac[lr*128 + chunk*8];
            }
#pragma unroll
            for (int c = 0; c < 4; ++c)
                bfr[c] = *(const short8*)&Bc[((ks*8 + cb + c)*64 + lane) << 3];
#pragma unroll
            for (int i = 0; i < 2; ++i)
#pragma unroll
                for (int c = 0; c < 4; ++c)
                    acc[i][c] = __builtin_amdgcn_mfma_f32_16x16x32_bf16(af[i], bfr[c], acc[i][c], 0, 0, 0);
        }
        __syncthreads();   // drains vmcnt(0): next A/B landed; current buffers free
        cur ^= 1;
    }

    // epilogue: store h2 + per-column BN2 partial sums
    float s[4], q[4];
#pragma unroll
    for (int c = 0; c < 4; ++c) { s[c] = 0.f; q[c] = 0.f; }
#pragma unroll
    for (int i = 0; i < 2; ++i)
#pragma unroll
        for (int c = 0; c < 4; ++c)
#pragma unroll
            for (int r = 0; r < 4; ++r) {
                int row = rowbase + wr*32 + i*16 + quad*4 + r;
                int col = (cb + c)*16 + l15;
                float v = acc[i][c][r];
                h2[row*128 + col] = v;
                s[c] += v; q[c] += v*v;
            }
    float* red = (float*)smem_raw;   // 256 floats: sums[128] | sqs[128]
    if (tid < 256) red[tid] = 0.f;
    __syncthreads();
#pragma unroll
    for (int c = 0; c < 4; ++c) {
        int col = (cb + c)*16 + l15;
        atomicAdd(&red[col], s[c]);
        atomicAdd(&red[128 + col], q[c]);
    }
    __syncthreads();
    if (tid < 256) atomicAdd(&gsum[tid], red[tid]);
}

// ---------------------------------------------------------------- final 1x1 conv, fused BN2+ReLU
__global__ __launch_bounds__(256) void out_kernel(const float* __restrict__ h2,
                                                  const float* __restrict__ wout,
                                                  const float* __restrict__ scale,
                                                  const float* __restrict__ shift,
                                                  float* __restrict__ out) {
    __shared__ float sc[128], sh[128];
    int tid = threadIdx.x;
    if (tid < 128) { sc[tid] = scale[tid]; sh[tid] = shift[tid]; }
    __syncthreads();
    int r = tid >> 4, d = tid & 15;
    int row = blockIdx.x * 16 + r;
    float acc = 0.f;
    for (int c = 0; c < 128; ++c) {
        float hv = fmaxf(0.f, fmaf(h2[row*128 + c], sc[c], sh[c]));
        acc = fmaf(hv, wout[c*16 + d], acc);
    }
    out[row*16 + d] = acc;
}

// ---------------------------------------------------------------- launch
extern "C" void kernel_launch(void* const* d_in, const int* in_sizes, int n_in,
                              void* d_out, int out_size, void* d_ws, size_t ws_size,
                              hipStream_t stream) {
    const int*   coords = (const int*)d_in[0];
    const float* feats  = (const float*)d_in[1];
    const float* w1     = (const float*)d_in[2];
    const float* g1     = (const float*)d_in[3];
    const float* b1     = (const float*)d_in[4];
    const float* w3     = (const float*)d_in[5];
    const float* g2     = (const float*)d_in[6];
    const float* b2     = (const float*)d_in[7];
    const float* wout   = (const float*)d_in[8];
    float* out = (float*)d_out;

    char* ws = (char*)d_ws;
    int*    table_base = (int*)(ws);                              // 4.03 MB
    int*    table   = table_base + GUARD;
    int*    packed  = (int*)(ws + (4352u<<10));                   // 128 KB
    int*    keyb    = (int*)(ws + (4608u<<10));                   // 128 KB
    int*    nbr     = (int*)(ws + (4864u<<10));                   // 1 MB
    int*    flagcnt = (int*)(ws + (5888u<<10));                   // 4 B
    int*    flaglist= (int*)(ws + (5892u<<10));                   // 128 KB
    float*  part    = (float*)(ws + (6144u<<10));                 // 256 KB (BN1 partials)
    float*  scale1  = (float*)(ws + (6400u<<10));
    float*  shift1  = scale1 + 128;
    float*  scale2  = shift1 + 128;
    float*  shift2  = scale2 + 128;
    float*  gsum    = (float*)(ws + (6416u<<10));                 // 1 KB (BN2 direct sums)
    ushort* w3f     = (ushort*)(ws + (6656u<<10));                // 0.88 MB (ends 7520K)
    ushort* hb      = (ushort*)(ws + (7680u<<10));                // 8 MB; hb-128 = 256B zero row
    float*  h       = (float*)(ws + (15872u<<10));                // 16 MB
    float*  h2      = h;   // aliased: h is dead once hb is written, conv3 reads only hb

    static bool conv3_attr_set = false;
    if (!conv3_attr_set) {
        hipFuncSetAttribute(reinterpret_cast<const void*>(&conv3_mfma_kernel),
                            hipFuncAttributeMaxDynamicSharedMemorySize, CONV3_LDS);
        conv3_attr_set = true;
    }

    hipMemsetAsync(table_base, 0xFF, (TBL + GUARD) * sizeof(int), stream);
    hipMemsetAsync(flagcnt, 0, sizeof(int), stream);
    prep_kernel      <<<N_/256, 256, 0, stream>>>(coords, table, packed, keyb,
                                                  gsum, (unsigned int*)(hb - 128));
    w3pack_kernel    <<<216, 256, 0, stream>>>(w3, w3f);
    knn_window_kernel<<<N_/64, 256, 0, stream>>>(table, keyb, nbr, flagcnt, flaglist);
    knn_bf_kernel    <<<256, 256, 0, stream>>>(packed, flagcnt, flaglist, nbr);
    h1_kernel        <<<N_/16, 256, 0, stream>>>(feats, nbr, w1, h);
    reduce_kernel    <<<N_/128, 256, 0, stream>>>(h, part);
    stats_kernel     <<<1, 128, 0, stream>>>(part, g1, b1, scale1, shift1);
    bnrelu_bf16_kernel<<<(N_*H_/4)/256, 256, 0, stream>>>(h, scale1, shift1, hb);
    conv3_mfma_kernel<<<N_/128, 512, CONV3_LDS, stream>>>(hb, w3f, table, keyb, h2, gsum);
    stats2_kernel    <<<1, 128, 0, stream>>>(gsum, g2, b2, scale2, shift2);
    out_kernel       <<<N_/16, 256, 0, stream>>>(h2, wout, scale2, shift2, out);
}

// Round 4
// 227.277 us; speedup vs baseline: 1.1650x; 1.0049x over previous
//
#include <hip/hip_runtime.h>
#include <hip/hip_bf16.h>

#define B_   4
#define M_   8192
#define N_   32768
#define H_   128
#define EPS_ 1e-5f
#define TBL  1048576   // 4 * 64^3 dense hash table
#define GUARD 8192     // negative-offset guard for window probes

typedef short short8 __attribute__((ext_vector_type(8)));   // 8 bf16 (4 VGPRs)
typedef float f32x4  __attribute__((ext_vector_type(4)));   // 4 fp32 acc

// ---------------------------------------------------------------- prep
__global__ __launch_bounds__(256) void prep_kernel(const int* __restrict__ coords,
                                                   int* __restrict__ table,
                                                   int* __restrict__ packed,
                                                   int* __restrict__ keyb,
                                                   float* __restrict__ gsum,
                                                   unsigned int* __restrict__ hbz) {
    int n = blockIdx.x * 256 + threadIdx.x;
    int b = coords[4*n+0], x = coords[4*n+1], y = coords[4*n+2], z = coords[4*n+3];
    packed[n] = (x << 10) | (y << 5) | z;
    int key = ((b*64 + x+1)*64 + y+1)*64 + (z+1);
    keyb[n] = key;
    table[key] = n;
    if (blockIdx.x == 0) gsum[threadIdx.x] = 0.f;            // 256 floats (BN2 stats acc)
    if (blockIdx.x == 1 && threadIdx.x < 64) hbz[threadIdx.x] = 0u;  // 256B zero row
}

// ---------------------------------------------------------------- w3 -> bf16 MFMA B-fragment layout
// w3f[t*8+j], t = (o<<11)|(ks<<9)|(ct<<6)|lane :
//   value = bf16(w3[o][c][n]), c = ks*32 + (lane>>4)*8 + j, n = ct*16 + (lane&15)
__global__ __launch_bounds__(256) void w3pack_kernel(const float* __restrict__ w3,
                                                     ushort* __restrict__ w3f) {
    int t = blockIdx.x * 256 + threadIdx.x;   // 27*2048 = 55296 threads exactly
    int lane = t & 63;
    int ct   = (t >> 6) & 7;
    int ks   = (t >> 9) & 3;
    int o    = t >> 11;
    int quad = lane >> 4, l15 = lane & 15;
    int n = ct*16 + l15;
    const float* src = w3 + o*16384;
    ushort out8[8];
#pragma unroll
    for (int j = 0; j < 8; ++j) {
        int c = ks*32 + quad*8 + j;
        float v = src[c*128 + n];
        __hip_bfloat16 bv = __float2bfloat16(v);
        ushort u; __builtin_memcpy(&u, &bv, 2);
        out8[j] = u;
    }
    *(uint4*)&w3f[t*8] = *(uint4*)out8;
}

// ---------------------------------------------------------------- kNN via radius-2 window
__global__ __launch_bounds__(256) void knn_window_kernel(const int* __restrict__ table,
                                                         const int* __restrict__ keyb,
                                                         int* __restrict__ nbr,
                                                         int* __restrict__ flagcnt,
                                                         int* __restrict__ flaglist) {
    __shared__ int okey_sh[125], d2_sh[125];
    __shared__ int tops[256 * 8];
    int tid = threadIdx.x;
    if (tid < 125) {
        int dx = tid / 25 - 2, rr = tid % 25, dy = rr / 5 - 2, dz = rr % 5 - 2;
        okey_sh[tid] = dx * 4096 + dy * 64 + dz;
        d2_sh[tid]   = dx*dx + dy*dy + dz*dz;
    }
    __syncthreads();

    int q   = blockIdx.x * 64 + (tid >> 2);
    int sub = tid & 3;
    int kb  = keyb[q];

    int top[8];
#pragma unroll
    for (int k = 0; k < 8; ++k) top[k] = 0x7FFFFFFF;

    int base = sub * 32;
    int cnt  = (sub == 3) ? 29 : 32;
    for (int i = 0; i < cnt; ++i) {
        int idx = base + i;
        int j = table[kb + okey_sh[idx]];
        if (j >= 0) {
            int key = (d2_sh[idx] << 13) | (j & 8191);
            if (key < top[7]) {
#pragma unroll
                for (int k = 7; k >= 1; --k)
                    top[k] = (key < top[k]) ? max(key, top[k-1]) : top[k];
                top[0] = min(key, top[0]);
            }
        }
    }
#pragma unroll
    for (int k = 0; k < 8; ++k) tops[tid*8 + k] = top[k];
    __syncthreads();

    if (sub == 0) {
        const int* L = &tops[tid*8];
        int ia0 = 0, ia1 = 0, ia2 = 0, ia3 = 0;
        int res[8];
#pragma unroll
        for (int k = 0; k < 8; ++k) {
            int v0 = L[ia0], v1 = L[8 + ia1], v2 = L[16 + ia2], v3 = L[24 + ia3];
            int m01 = min(v0, v1), m23 = min(v2, v3);
            int m = min(m01, m23);
            res[k] = m;
            if (m == v0) ++ia0; else if (m == v1) ++ia1;
            else if (m == v2) ++ia2; else ++ia3;
        }
        int bb = q & ~(M_-1);
        if ((res[7] >> 13) <= 8) {
#pragma unroll
            for (int k = 0; k < 8; ++k) nbr[q*8 + k] = bb + (res[k] & 8191);
        } else {
            int pos = atomicAdd(flagcnt, 1);
            flaglist[pos] = q;
        }
    }
}

// ---------------------------------------------------------------- brute-force cleanup
__global__ __launch_bounds__(256) void knn_bf_kernel(const int* __restrict__ packed,
                                                     const int* __restrict__ flagcnt,
                                                     const int* __restrict__ flaglist,
                                                     int* __restrict__ nbr) {
    __shared__ int tops[256 * 8];
    int tid = threadIdx.x;
    int cnt = *flagcnt;
    for (int f = blockIdx.x; f < cnt; f += gridDim.x) {
        int n = flaglist[f];
        int bb = n & ~(M_-1);
        int p = packed[n];
        int qx = (p >> 10) & 31, qy = (p >> 5) & 31, qz = p & 31;
        int top[8];
#pragma unroll
        for (int k = 0; k < 8; ++k) top[k] = 0x7FFFFFFF;
        for (int j = tid; j < M_; j += 256) {
            int c = packed[bb + j];
            int dx = qx - ((c >> 10) & 31);
            int dy = qy - ((c >> 5) & 31);
            int dz = qz - (c & 31);
            int d2 = dx*dx + dy*dy + dz*dz;
            int key = (d2 << 13) | j;
            if (key < top[7]) {
#pragma unroll
                for (int k = 7; k >= 1; --k)
                    top[k] = (key < top[k]) ? max(key, top[k-1]) : top[k];
                top[0] = min(key, top[0]);
            }
        }
#pragma unroll
        for (int k = 0; k < 8; ++k) tops[tid*8 + k] = top[k];
        __syncthreads();
        for (int stride = 128; stride >= 1; stride >>= 1) {
            if (tid < stride) {
                int* A  = &tops[tid*8];
                int* Bp = &tops[(tid+stride)*8];
                int r[8]; int ia = 0, ib = 0;
#pragma unroll
                for (int k = 0; k < 8; ++k) {
                    int a = A[ia], b2 = Bp[ib];
                    if (a <= b2) { r[k] = a; ++ia; } else { r[k] = b2; ++ib; }
                }
#pragma unroll
                for (int k = 0; k < 8; ++k) A[k] = r[k];
            }
            __syncthreads();
        }
        if (tid == 0) {
#pragma unroll
            for (int k = 0; k < 8; ++k) nbr[n*8 + k] = bb + (tops[k] & 8191);
        }
        __syncthreads();
    }
}

// ---------------------------------------------------------------- 1x1 conv (combined @ w1)
__global__ __launch_bounds__(256) void h1_kernel(const float* __restrict__ feats,
                                                 const int* __restrict__ nbr,
                                                 const float* __restrict__ w1,
                                                 float* __restrict__ hpre) {
    __shared__ float comb[16][72];
    int tid = threadIdx.x;
    int rowbase = blockIdx.x * 16;
    if (tid < 144) {
        int r = tid / 9, s = tid % 9;
        int grow = rowbase + r;
        int idx = (s == 0) ? grow : nbr[grow*8 + (s-1)];
        const float4* f = (const float4*)(feats + idx * 8);
        float4 a = f[0], b = f[1];
        float* dp = &comb[r][s*8];
        dp[0]=a.x; dp[1]=a.y; dp[2]=a.z; dp[3]=a.w;
        dp[4]=b.x; dp[5]=b.y; dp[6]=b.z; dp[7]=b.w;
    }
    __syncthreads();
    int c = tid & 127, rh = tid >> 7;
    float acc[8];
#pragma unroll
    for (int i = 0; i < 8; ++i) acc[i] = 0.f;
    for (int s = 0; s < 72; ++s) {
        float w = w1[s*128 + c];
#pragma unroll
        for (int i = 0; i < 8; ++i)
            acc[i] += comb[rh*8 + i][s] * w;
    }
#pragma unroll
    for (int i = 0; i < 8; ++i)
        hpre[(rowbase + rh*8 + i)*128 + c] = acc[i];
}

// ---------------------------------------------------------------- BN stats (h1 path)
__global__ __launch_bounds__(256) void reduce_kernel(const float* __restrict__ src,
                                                     float* __restrict__ part) {
    __shared__ float ssum[256], ssq[256];
    int tid = threadIdx.x;
    int c = tid & 127, halfr = tid >> 7;
    int rowbase = blockIdx.x * 128 + halfr * 64;
    float s = 0.f, q = 0.f;
    for (int i = 0; i < 64; ++i) {
        float v = src[(rowbase + i)*128 + c];
        s += v; q += v*v;
    }
    ssum[tid] = s; ssq[tid] = q;
    __syncthreads();
    if (tid < 128) {
        part[blockIdx.x*256 + tid]       = ssum[tid] + ssum[tid+128];
        part[blockIdx.x*256 + 128 + tid] = ssq[tid]  + ssq[tid+128];
    }
}

__global__ __launch_bounds__(128) void stats_kernel(const float* __restrict__ part,
                                                    const float* __restrict__ g,
                                                    const float* __restrict__ bias,
                                                    float* __restrict__ scale,
                                                    float* __restrict__ shift) {
    int c = threadIdx.x;
    float s = 0.f, q = 0.f;
    for (int b = 0; b < 256; ++b) {
        s += part[b*256 + c];
        q += part[b*256 + 128 + c];
    }
    float mu  = s / (float)N_;
    float var = q / (float)N_ - mu*mu;
    float inv = rsqrtf(var + EPS_);
    float sc  = inv * g[c];
    scale[c] = sc;
    shift[c] = bias[c] - mu * sc;
}

// BN2 stats from direct sums (conv3 epilogue accumulates gsum)
__global__ __launch_bounds__(128) void stats2_kernel(const float* __restrict__ gsum,
                                                     const float* __restrict__ g,
                                                     const float* __restrict__ bias,
                                                     float* __restrict__ scale,
                                                     float* __restrict__ shift) {
    int c = threadIdx.x;
    float s = gsum[c], q = gsum[128 + c];
    float mu  = s / (float)N_;
    float var = q / (float)N_ - mu*mu;
    float inv = rsqrtf(var + EPS_);
    float sc  = inv * g[c];
    scale[c] = sc;
    shift[c] = bias[c] - mu * sc;
}

// BN+ReLU -> bf16 output (for conv3 A operand)
__global__ __launch_bounds__(256) void bnrelu_bf16_kernel(const float* __restrict__ x,
                                                          const float* __restrict__ scale,
                                                          const float* __restrict__ shift,
                                                          ushort* __restrict__ y) {
    int i = blockIdx.x * 256 + threadIdx.x;
    float4 v = ((const float4*)x)[i];
    int c = (i * 4) & 127;
    v.x = fmaxf(0.f, v.x*scale[c]   + shift[c]);
    v.y = fmaxf(0.f, v.y*scale[c+1] + shift[c+1]);
    v.z = fmaxf(0.f, v.z*scale[c+2] + shift[c+2]);
    v.w = fmaxf(0.f, v.w*scale[c+3] + shift[c+3]);
    ushort o[4];
#pragma unroll
    for (int k = 0; k < 4; ++k) {
        float f = (&v.x)[k];
        __hip_bfloat16 bv = __float2bfloat16(f);
        __builtin_memcpy(&o[k], &bv, 2);
    }
    ((ushort4*)y)[i] = make_ushort4(o[0], o[1], o[2], o[3]);
}

// ---------------------------------------------------------------- 3^3 sparse conv: deep-pipelined bf16 MFMA gather-GEMM
// block: 128 rows x 128 cols, 8 waves (each 32 rows x 64 cols = 2x4 tiles of 16x16)
// R4: counted-vmcnt pipeline (T3/T4). A-ring 3x32KB (issued 2 iters ahead),
// B-ring 2x32KB (1 ahead) = 160 KB LDS exactly. Per-iter: s_waitcnt vmcnt(4)
// (never 0) + raw s_barrier -> A(o+1) stays in flight across the barrier.
// j-indices live in registers, loaded 1 iter ahead (table[] gather, 16-lane dup
// -> broadcast-coalesced). Tail uniformity via index clamping (redundant writes
// land in already-consumed slots).
#define CONV3_LDS 163840
#define GLL(src, dst) __builtin_amdgcn_global_load_lds( \
    (const __attribute__((address_space(1))) unsigned int*)(src), \
    (__attribute__((address_space(3))) unsigned int*)(dst), 16, 0, 0)

__device__ __forceinline__ int okey_of(int o) {
    int dx = o/9 - 1, dy = (o/3)%3 - 1, dz = o%3 - 1;
    return dx*4096 + dy*64 + dz;
}

__global__ __launch_bounds__(512) void conv3_mfma_kernel(const ushort* __restrict__ hb,
                                                         const ushort* __restrict__ w3f,
                                                         const int* __restrict__ table,
                                                         const int* __restrict__ keyb,
                                                         float* __restrict__ h2,
                                                         float* __restrict__ gsum) {
    extern __shared__ char smem_raw[];
    // A ring slots at 0 / 32768 / 65536 ; B ring slots at 98304 / 131072
    int tid = threadIdx.x;
    int lane = tid & 63, wid = tid >> 6;
    int quad = lane >> 4, l15 = lane & 15;
    int bid = blockIdx.x;
    int swz = (bid & 7) * 32 + (bid >> 3);   // XCD-chunked, bijective (256 % 8 == 0)
    int rowbase = swz * 128;
    int wr = wid >> 1;              // row group 0..3 (32 rows each)
    int cb = (wid & 1) * 4;         // col-tile base (0 or 4)

    // staging geometry: thread covers rows r_i = i*32 + (tid>>4), chunk cp = tid&15
    int r0 = tid >> 4;
    int swzoff = ((tid & 15) ^ (r0 & 15)) << 3;   // swizzled element offset within row
    int kb0 = keyb[rowbase + r0];
    int kb1 = keyb[rowbase + r0 + 32];
    int kb2 = keyb[rowbase + r0 + 64];
    int kb3 = keyb[rowbase + r0 + 96];

    // prologue: j for o=0,1,2 ; stage A(0), B(0), A(1)
    int ok0 = okey_of(0), ok1 = okey_of(1), ok2 = okey_of(2);
    int j00 = table[kb0+ok0], j01 = table[kb1+ok0], j02 = table[kb2+ok0], j03 = table[kb3+ok0];
    int j10 = table[kb0+ok1], j11 = table[kb1+ok1], j12 = table[kb2+ok1], j13 = table[kb3+ok1];
    int jc0 = table[kb0+ok2], jc1 = table[kb1+ok2], jc2 = table[kb2+ok2], jc3 = table[kb3+ok2];

    GLL(hb + j00*128 + swzoff, smem_raw + 0     + ((0*512+tid) << 4));
    GLL(hb + j01*128 + swzoff, smem_raw + 0     + ((1*512+tid) << 4));
    GLL(hb + j02*128 + swzoff, smem_raw + 0     + ((2*512+tid) << 4));
    GLL(hb + j03*128 + swzoff, smem_raw + 0     + ((3*512+tid) << 4));
#pragma unroll
    for (int i = 0; i < 4; ++i) {
        int flat = i*512 + tid;
        GLL(w3f + flat*8, smem_raw + 98304 + (flat << 4));
    }
    GLL(hb + j10*128 + swzoff, smem_raw + 32768 + ((0*512+tid) << 4));
    GLL(hb + j11*128 + swzoff, smem_raw + 32768 + ((1*512+tid) << 4));
    GLL(hb + j12*128 + swzoff, smem_raw + 32768 + ((2*512+tid) << 4));
    GLL(hb + j13*128 + swzoff, smem_raw + 32768 + ((3*512+tid) << 4));

    f32x4 acc[2][4];
#pragma unroll
    for (int i = 0; i < 2; ++i)
#pragma unroll
        for (int c = 0; c < 4; ++c)
            acc[i][c] = (f32x4){0.f, 0.f, 0.f, 0.f};

    int aRd = 0, aNx = 32768, aW = 65536;     // A ring byte offsets
    int bRd = 98304, bW = 131072;             // B ring byte offsets

#pragma unroll 1
    for (int o = 0; o < 27; ++o) {
        // counted drain: leaves the newest 4 (A(o+1)) in flight across the barrier
        asm volatile("s_waitcnt vmcnt(4)" ::: "memory");
        __builtin_amdgcn_s_barrier();

        // j(o+3) -> registers (used by A-issue next iter)
        int on = (o+3 < 27) ? o+3 : 26;
        int okn = okey_of(on);
        int jn0 = table[kb0+okn], jn1 = table[kb1+okn], jn2 = table[kb2+okn], jn3 = table[kb3+okn];

        // B(o+1) -> bW (slot last read at compute(o-1); all waves past barrier)
        int ob = (o+1 < 27) ? o+1 : 26;
        const ushort* wsrc = w3f + (ob << 14);
#pragma unroll
        for (int i = 0; i < 4; ++i) {
            int flat = i*512 + tid;
            GLL(wsrc + flat*8, smem_raw + bW + (flat << 4));
        }
        // A(o+2) -> aW, using j(o+2) (jc*, drained by this iter's vmcnt)
        GLL(hb + jc0*128 + swzoff, smem_raw + aW + ((0*512+tid) << 4));
        GLL(hb + jc1*128 + swzoff, smem_raw + aW + ((1*512+tid) << 4));
        GLL(hb + jc2*128 + swzoff, smem_raw + aW + ((2*512+tid) << 4));
        GLL(hb + jc3*128 + swzoff, smem_raw + aW + ((3*512+tid) << 4));

        // compute(o): conflict-free ds_read_b128 + MFMA only
        const ushort* Ac = (const ushort*)(smem_raw + aRd);
        const ushort* Bc = (const ushort*)(smem_raw + bRd);
#pragma unroll
        for (int ks = 0; ks < 4; ++ks) {
            short8 af[2], bfr[4];
#pragma unroll
            for (int i = 0; i < 2; ++i) {
                int lr = wr*32 + i*16 + l15;
                int chunk = (ks*4 + quad) ^ l15;
                af[i] = *(const short8*)&Ac[lr*128 + chunk*8];
            }
#pragma unroll
            for (int c = 0; c < 4; ++c)
                bfr[c] = *(const short8*)&Bc[((ks*8 + cb + c)*64 + lane) << 3];
#pragma unroll
            for (int i = 0; i < 2; ++i)
#pragma unroll
                for (int c = 0; c < 4; ++c)
                    acc[i][c] = __builtin_amdgcn_mfma_f32_16x16x32_bf16(af[i], bfr[c], acc[i][c], 0, 0, 0);
        }

        // rotate rings + j registers
        jc0 = jn0; jc1 = jn1; jc2 = jn2; jc3 = jn3;
        int t = aRd; aRd = aNx; aNx = aW; aW = t;
        t = bRd; bRd = bW; bW = t;
    }

    __syncthreads();   // full drain before LDS reuse

    // epilogue: store h2 + per-column BN2 partial sums
    float s[4], q[4];
#pragma unroll
    for (int c = 0; c < 4; ++c) { s[c] = 0.f; q[c] = 0.f; }
#pragma unroll
    for (int i = 0; i < 2; ++i)
#pragma unroll
        for (int c = 0; c < 4; ++c)
#pragma unroll
            for (int r = 0; r < 4; ++r) {
                int row = rowbase + wr*32 + i*16 + quad*4 + r;
                int col = (cb + c)*16 + l15;
                float v = acc[i][c][r];
                h2[row*128 + col] = v;
                s[c] += v; q[c] += v*v;
            }
    float* red = (float*)smem_raw;   // 256 floats: sums[128] | sqs[128]
    if (tid < 256) red[tid] = 0.f;
    __syncthreads();
#pragma unroll
    for (int c = 0; c < 4; ++c) {
        int col = (cb + c)*16 + l15;
        atomicAdd(&red[col], s[c]);
        atomicAdd(&red[128 + col], q[c]);
    }
    __syncthreads();
    if (tid < 256) atomicAdd(&gsum[tid], red[tid]);
}

// ---------------------------------------------------------------- final 1x1 conv, fused BN2+ReLU
__global__ __launch_bounds__(256) void out_kernel(const float* __restrict__ h2,
                                                  const float* __restrict__ wout,
                                                  const float* __restrict__ scale,
                                                  const float* __restrict__ shift,
                                                  float* __restrict__ out) {
    __shared__ float sc[128], sh[128];
    int tid = threadIdx.x;
    if (tid < 128) { sc[tid] = scale[tid]; sh[tid] = shift[tid]; }
    __syncthreads();
    int r = tid >> 4, d = tid & 15;
    int row = blockIdx.x * 16 + r;
    float acc = 0.f;
    for (int c = 0; c < 128; ++c) {
        float hv = fmaxf(0.f, fmaf(h2[row*128 + c], sc[c], sh[c]));
        acc = fmaf(hv, wout[c*16 + d], acc);
    }
    out[row*16 + d] = acc;
}

// ---------------------------------------------------------------- launch
extern "C" void kernel_launch(void* const* d_in, const int* in_sizes, int n_in,
                              void* d_out, int out_size, void* d_ws, size_t ws_size,
                              hipStream_t stream) {
    const int*   coords = (const int*)d_in[0];
    const float* feats  = (const float*)d_in[1];
    const float* w1     = (const float*)d_in[2];
    const float* g1     = (const float*)d_in[3];
    const float* b1     = (const float*)d_in[4];
    const float* w3     = (const float*)d_in[5];
    const float* g2     = (const float*)d_in[6];
    const float* b2     = (const float*)d_in[7];
    const float* wout   = (const float*)d_in[8];
    float* out = (float*)d_out;

    char* ws = (char*)d_ws;
    int*    table_base = (int*)(ws);                              // 4.03 MB
    int*    table   = table_base + GUARD;
    int*    packed  = (int*)(ws + (4352u<<10));                   // 128 KB
    int*    keyb    = (int*)(ws + (4608u<<10));                   // 128 KB
    int*    nbr     = (int*)(ws + (4864u<<10));                   // 1 MB
    int*    flagcnt = (int*)(ws + (5888u<<10));                   // 4 B
    int*    flaglist= (int*)(ws + (5892u<<10));                   // 128 KB
    float*  part    = (float*)(ws + (6144u<<10));                 // 256 KB (BN1 partials)
    float*  scale1  = (float*)(ws + (6400u<<10));
    float*  shift1  = scale1 + 128;
    float*  scale2  = shift1 + 128;
    float*  shift2  = scale2 + 128;
    float*  gsum    = (float*)(ws + (6416u<<10));                 // 1 KB (BN2 direct sums)
    ushort* w3f     = (ushort*)(ws + (6656u<<10));                // 0.88 MB (ends 7520K)
    ushort* hb      = (ushort*)(ws + (7680u<<10));                // 8 MB; hb-128 = 256B zero row
    float*  h       = (float*)(ws + (15872u<<10));                // 16 MB
    float*  h2      = h;   // aliased: h is dead once hb is written, conv3 reads only hb

    static bool conv3_attr_set = false;
    if (!conv3_attr_set) {
        hipFuncSetAttribute(reinterpret_cast<const void*>(&conv3_mfma_kernel),
                            hipFuncAttributeMaxDynamicSharedMemorySize, CONV3_LDS);
        conv3_attr_set = true;
    }

    hipMemsetAsync(table_base, 0xFF, (TBL + GUARD) * sizeof(int), stream);
    hipMemsetAsync(flagcnt, 0, sizeof(int), stream);
    prep_kernel      <<<N_/256, 256, 0, stream>>>(coords, table, packed, keyb,
                                                  gsum, (unsigned int*)(hb - 128));
    w3pack_kernel    <<<216, 256, 0, stream>>>(w3, w3f);
    knn_window_kernel<<<N_/64, 256, 0, stream>>>(table, keyb, nbr, flagcnt, flaglist);
    knn_bf_kernel    <<<256, 256, 0, stream>>>(packed, flagcnt, flaglist, nbr);
    h1_kernel        <<<N_/16, 256, 0, stream>>>(feats, nbr, w1, h);
    reduce_kernel    <<<N_/128, 256, 0, stream>>>(h, part);
    stats_kernel     <<<1, 128, 0, stream>>>(part, g1, b1, scale1, shift1);
    bnrelu_bf16_kernel<<<(N_*H_/4)/256, 256, 0, stream>>>(h, scale1, shift1, hb);
    conv3_mfma_kernel<<<N_/128, 512, CONV3_LDS, stream>>>(hb, w3f, table, keyb, h2, gsum);
    stats2_kernel    <<<1, 128, 0, stream>>>(gsum, g2, b2, scale2, shift2);
    out_kernel       <<<N_/16, 256, 0, stream>>>(h2, wout, scale2, shift2, out);
}